// Round 10
// baseline (681.931 us; speedup 1.0000x reference)
//
#include <hip/hip_runtime.h>
#include <math.h>

#define N_NODES 50000
#define M_PAD   50048    // N_NODES padded to multiple of 128 for MFMA tiles
#define N_EDGES 600000
#define E_TOT   650000   // N_EDGES + N_NODES (self loops appended)
#define F_IN    128
#define HID     64
#define HEADS   8
#define H1      512      // HEADS*HID
#define NCLS    16
#define NC      16
#define NCP     16
#define NBLK    ((N_NODES + 255) / 256)   // 196 scan blocks per array

typedef unsigned short u16;
typedef unsigned char  u8;
typedef __attribute__((ext_vector_type(8))) short short8;   // 8 bf16 = 4 VGPRs (MFMA A/B frag)
typedef __attribute__((ext_vector_type(4))) float f32x4;    // MFMA C/D frag
typedef __attribute__((ext_vector_type(2))) float f32x2;

__device__ __forceinline__ float bf2f(u16 h) {
    return __uint_as_float(((unsigned)h) << 16);
}
__device__ __forceinline__ u16 f2bf(float f) {
    unsigned u = __float_as_uint(f);
    u += 0x7fffu + ((u >> 16) & 1u);
    return (u16)(u >> 16);
}
__device__ __forceinline__ int edge_src(const int* __restrict__ ei, int e) {
    return (e < N_EDGES) ? ei[e] : (e - N_EDGES);
}
__device__ __forceinline__ int edge_dst(const int* __restrict__ ei, int e) {
    return (e < N_EDGES) ? ei[N_EDGES + e] : (e - N_EDGES);
}

// ---------------- CSR build ----------------
__global__ __launch_bounds__(256) void count_k(const int* __restrict__ ei,
                                               int* __restrict__ src_cnt, int* __restrict__ dst_cnt) {
    int e = blockIdx.x * 256 + threadIdx.x;
    if (e >= E_TOT) return;
    atomicAdd(&src_cnt[edge_src(ei, e)], 1);
    atomicAdd(&dst_cnt[edge_dst(ei, e)], 1);
}

// Phase A: per-block partial sums. grid = 2*NBLK (src blocks, then dst blocks).
__global__ __launch_bounds__(256) void scanA_k(const int* __restrict__ src_cnt,
                                               const int* __restrict__ dst_cnt,
                                               int* __restrict__ partials) {
    int pass = blockIdx.x >= NBLK;
    int b = blockIdx.x - pass * NBLK;
    const int* cnt = pass ? dst_cnt : src_cnt;
    int idx = b * 256 + threadIdx.x;
    int v = (idx < N_NODES) ? cnt[idx] : 0;
    __shared__ int red[4];
    #pragma unroll
    for (int off = 32; off; off >>= 1) v += __shfl_down(v, off, 64);
    if ((threadIdx.x & 63) == 0) red[threadIdx.x >> 6] = v;
    __syncthreads();
    if (threadIdx.x == 0) partials[blockIdx.x] = red[0] + red[1] + red[2] + red[3];
}

// Phase B: two independent exclusive scans of NBLK partials (src seg, dst seg), one block.
__global__ __launch_bounds__(512) void scanB_k(int* __restrict__ partials) {
    __shared__ int lds[512];
    int t = threadIdx.x;           // 512 threads: t<256 -> src segment, else dst
    int seg = t >> 8, i = t & 255;
    int v = (i < NBLK) ? partials[seg * NBLK + i] : 0;
    lds[t] = v;
    __syncthreads();
    for (int d = 1; d < 256; d <<= 1) {
        int x = (i >= d) ? lds[seg * 256 + i - d] : 0;
        __syncthreads();
        lds[t] += x;
        __syncthreads();
    }
    if (i < NBLK) partials[seg * NBLK + i] = lds[t] - v;   // exclusive
}

// Phase C: block-local exclusive scan + block offset -> off[]; off[N]=E_TOT constant.
__global__ __launch_bounds__(256) void scanC_k(const int* __restrict__ src_cnt,
                                               const int* __restrict__ dst_cnt,
                                               const int* __restrict__ partials,
                                               int* __restrict__ src_off, int* __restrict__ dst_off) {
    int pass = blockIdx.x >= NBLK;
    int b = blockIdx.x - pass * NBLK;
    const int* cnt = pass ? dst_cnt : src_cnt;
    int* off = pass ? dst_off : src_off;
    int base = partials[blockIdx.x];
    __shared__ int lds[256];
    int t = threadIdx.x;
    int idx = b * 256 + t;
    int v = (idx < N_NODES) ? cnt[idx] : 0;
    lds[t] = v;
    __syncthreads();
    for (int d = 1; d < 256; d <<= 1) {
        int x = (t >= d) ? lds[t - d] : 0;
        __syncthreads();
        lds[t] += x;
        __syncthreads();
    }
    if (idx < N_NODES) off[idx] = base + lds[t] - v;
    if (b == 0 && t == 0) off[N_NODES] = E_TOT;
}

// fill: rkd[e] = slot of e in dst-CSR; dsrc[slot] = src node; src_list[src slot] = dst-slot id
__global__ __launch_bounds__(256) void fill_csr_k(const int* __restrict__ ei,
                                                  const int* __restrict__ src_off, const int* __restrict__ dst_off,
                                                  int* __restrict__ src_cur, int* __restrict__ dst_cur,
                                                  int* __restrict__ src_list, int* __restrict__ rkd,
                                                  int* __restrict__ dsrc) {
    int e = blockIdx.x * 256 + threadIdx.x;
    if (e >= E_TOT) return;
    int s = edge_src(ei, e), d = edge_dst(ei, e);
    int pd = atomicAdd(&dst_cur[d], 1);
    int rd = dst_off[d] + pd;
    rkd[e] = rd;
    dsrc[rd] = s;
    int ps = atomicAdd(&src_cur[s], 1);
    src_list[src_off[s] + ps] = rd;
}

// ---------------- layout converters ----------------
// f32 [M][K] row-major -> bf16 fragment-major Ap[K/8][Mp][8]; pad rows zeroed
__global__ __launch_bounds__(256) void conv_a_k(const float* __restrict__ A, u16* __restrict__ Ap,
                                                int M, int Mp, int K) {
    int i = blockIdx.x * 256 + threadIdx.x;
    int total = (K >> 3) * Mp;
    if (i >= total) return;
    int r = i % Mp;
    int kb = i / Mp;
    u16* o = Ap + (size_t)i * 8;
    u16 tmp[8];
    if (r < M) {
        const float* a = A + (size_t)r * K + kb * 8;
        #pragma unroll
        for (int j = 0; j < 8; ++j) tmp[j] = f2bf(a[j]);
    } else {
        #pragma unroll
        for (int j = 0; j < 8; ++j) tmp[j] = 0;
    }
    *(ushort4*)o = *(ushort4*)tmp;
    *(ushort4*)(o + 4) = *(ushort4*)(tmp + 4);
}

// f32 [K][N] row-major -> bf16 fragment-major Bp[K/8][N][8] (Bp[kb][n][j] = B[kb*8+j][n])
__global__ __launch_bounds__(256) void conv_b_k(const float* __restrict__ B, u16* __restrict__ Bp,
                                                int K, int N) {
    int i = blockIdx.x * 256 + threadIdx.x;
    int total = (K >> 3) * N;
    if (i >= total) return;
    int n = i % N;
    int kb = i / N;
    u16 tmp[8];
    #pragma unroll
    for (int j = 0; j < 8; ++j) tmp[j] = f2bf(B[(size_t)(kb * 8 + j) * N + n]);
    u16* o = Bp + (size_t)i * 8;
    *(ushort4*)o = *(ushort4*)tmp;
    *(ushort4*)(o + 4) = *(ushort4*)(tmp + 4);
}

// all 4 edge-MLP weight tables -> per-lane B-frag layout, one launch
__device__ __forceinline__ void wfrag_one(const float* W, u16* o, int i, int K, int N) {
    int j = i & 7, lane = (i >> 3) & 63, rest = i >> 9;
    int nt = rest % (N / 16), ks = rest / (N / 16);
    int lm = lane & 15, quad = lane >> 4;
    int k = ks * 32 + quad * 8 + j, n = nt * 16 + lm;
    o[i] = (k < K) ? f2bf(W[(size_t)k * N + n]) : (u16)0;
}
__global__ __launch_bounds__(256) void wfrag_all_k(
    const float* __restrict__ h1w1, const float* __restrict__ h1w2,
    const float* __restrict__ h2w1, const float* __restrict__ h2w2,
    u16* __restrict__ w1f, u16* __restrict__ w2f,
    u16* __restrict__ w3f, u16* __restrict__ w4f) {
    int i = blockIdx.x * 256 + threadIdx.x;   // total 2048+4096+512+512 = 7168
    if (i < 2048)      wfrag_one(h1w1, w1f, i, 16, 64);          // Kpad 32, N 64
    else if (i < 6144) wfrag_one(h1w2, w2f, i - 2048, 64, 64);   // Kpad 64, N 64
    else if (i < 6656) wfrag_one(h2w1, w3f, i - 6144, 16, 16);
    else if (i < 7168) wfrag_one(h2w2, w4f, i - 6656, 16, 16);
}

// ---------------- MFMA GEMM: C[M][N] = epi(Ap @ Bp), frag-major operands, no LDS ----------------
// K-loop is register double-buffered: iteration k+1's 8 fragment loads are issued before
// iteration k's MFMAs, so the wave always has 8 loads in flight during compute (vmcnt(8)
// instead of vmcnt(0) stalls).
template<int EPI>
__global__ __launch_bounds__(256) void mfma_gemm_k(
    const u16* __restrict__ Ap, const u16* __restrict__ Bp, u16* __restrict__ C,
    int M, int Mp, int Nn, int K,
    const float* __restrict__ bias, const u16* __restrict__ extra,
    const float* __restrict__ bias2, const float* __restrict__ alpha_p)
{
    const int t = threadIdx.x;
    const int wave = t >> 6, lane = t & 63;
    const int wm = (wave >> 1) * 64, wn = (wave & 1) * 64;
    const int bm = blockIdx.y * 128, bn = blockIdx.x * 128;
    const int lm = lane & 15, quad = lane >> 4;

    size_t rbase[4], cbase[4];
    #pragma unroll
    for (int mi = 0; mi < 4; ++mi) rbase[mi] = (size_t)(bm + wm + mi * 16 + lm) * 8;
    #pragma unroll
    for (int nj = 0; nj < 4; ++nj) cbase[nj] = (size_t)(bn + wn + nj * 16 + lm) * 8;

    f32x4 acc[4][4] = {};

    // prologue: load k0 = 0 fragments
    short8 af[4], bf_[4];
    {
        int kb = quad;
        size_t abase = (size_t)kb * Mp * 8;
        size_t bbase = (size_t)kb * Nn * 8;
        #pragma unroll
        for (int mi = 0; mi < 4; ++mi) af[mi] = *(const short8*)(Ap + abase + rbase[mi]);
        #pragma unroll
        for (int nj = 0; nj < 4; ++nj) bf_[nj] = *(const short8*)(Bp + bbase + cbase[nj]);
    }

    for (int k0 = 0; k0 < K; k0 += 32) {
        short8 afn[4], bfn[4];
        const bool more = (k0 + 32 < K);
        if (more) {
            int kb = ((k0 + 32) >> 3) + quad;
            size_t abase = (size_t)kb * Mp * 8;
            size_t bbase = (size_t)kb * Nn * 8;
            #pragma unroll
            for (int mi = 0; mi < 4; ++mi) afn[mi] = *(const short8*)(Ap + abase + rbase[mi]);
            #pragma unroll
            for (int nj = 0; nj < 4; ++nj) bfn[nj] = *(const short8*)(Bp + bbase + cbase[nj]);
        }
        #pragma unroll
        for (int mi = 0; mi < 4; ++mi)
            #pragma unroll
            for (int nj = 0; nj < 4; ++nj)
                acc[mi][nj] = __builtin_amdgcn_mfma_f32_16x16x32_bf16(af[mi], bf_[nj], acc[mi][nj], 0, 0, 0);
        if (more) {
            #pragma unroll
            for (int mi = 0; mi < 4; ++mi) af[mi] = afn[mi];
            #pragma unroll
            for (int nj = 0; nj < 4; ++nj) bf_[nj] = bfn[nj];
        }
    }

    // C/D layout: col = lane&15, row = quad*4 + reg
    const int orow = bm + wm + quad * 4;
    const int ocol = bn + wn + lm;
    if (EPI == 0) {
        #pragma unroll
        for (int mi = 0; mi < 4; ++mi)
            #pragma unroll
            for (int r = 0; r < 4; ++r) {
                int rr = orow + mi * 16 + r;
                if (rr >= M) continue;
                #pragma unroll
                for (int nj = 0; nj < 4; ++nj)
                    C[(size_t)rr * Nn + ocol + nj * 16] = f2bf(acc[mi][nj][r]);
            }
    } else {
        float alpha = *alpha_p;
        #pragma unroll
        for (int mi = 0; mi < 4; ++mi)
            #pragma unroll
            for (int r = 0; r < 4; ++r) {
                int rr = orow + mi * 16 + r;
                if (rr >= M) continue;
                #pragma unroll
                for (int nj = 0; nj < 4; ++nj) {
                    int c = ocol + nj * 16;
                    float v = acc[mi][nj][r] + bias[c];
                    v = v > 0.f ? v : 0.01f * v;
                    float o = bf2f(extra[(size_t)rr * Nn + c]) + bias2[c] + alpha * v;
                    o = fmaxf(o, 0.f);
                    C[(size_t)rr * Nn + c] = f2bf(o);
                }
            }
    }
}

// ---------------- t1 = leaky(ep @ p1w1, 0.2), K=16, written in frag-major Ap layout ----------------
__global__ __launch_bounds__(256) void gemm_t1_k(
    const float* __restrict__ ep, const float* __restrict__ W, u16* __restrict__ t1p)
{
    __shared__ float Bs[16][64];
    const int bm = blockIdx.y * 64, bn = blockIdx.x * 64;
    const int t = threadIdx.x;
    const int tx = t & 15, ty = t >> 4;
    *(float4*)&Bs[t >> 4][(t & 15) * 4] = *(const float4*)&W[(size_t)(t >> 4) * H1 + bn + (t & 15) * 4];
    __syncthreads();
    const int r0 = bm + ty * 4;
    const int c0 = bn + tx * 4;
    for (int i = 0; i < 4; ++i) {
        int r = r0 + i;
        if (r >= N_NODES) continue;
        float av[16];
        #pragma unroll
        for (int j4 = 0; j4 < 16; j4 += 4) {
            float4 v = *(const float4*)(ep + (size_t)r * NCP + j4);
            av[j4] = v.x; av[j4 + 1] = v.y; av[j4 + 2] = v.z; av[j4 + 3] = v.w;
        }
        u16 pk[4];
        #pragma unroll
        for (int q = 0; q < 4; ++q) {
            float s = 0.f;
            #pragma unroll
            for (int k = 0; k < 16; ++k) s = fmaf(av[k], Bs[k][tx * 4 + q], s);
            s = s > 0.f ? s : 0.2f * s;
            pk[q] = f2bf(s);
        }
        u16* o = t1p + ((size_t)(c0 >> 3) * M_PAD + r) * 8 + (c0 & 7);
        *(ushort4*)o = *(ushort4*)pk;
    }
}

// ---------------- N=16 GEMM (xh2 = h @ W_src2), bf16 A, K multiple of 64 ----------------
__global__ __launch_bounds__(256) void gemm_n16_k(
    const u16* __restrict__ A, const float* __restrict__ B, float* __restrict__ C,
    int M, int K)
{
    __shared__ float As[16][64];   // [row][k]
    __shared__ float Bs[64][16];   // [k][col]
    const int row0 = blockIdx.x * 16;
    const int t = threadIdx.x;
    const int r = t >> 4, c = t & 15;
    const int ar = t >> 4, ak4 = (t & 15) * 4;
    const int bk = t >> 2, bc4 = (t & 3) * 4;
    float acc = 0.f;
    for (int k0 = 0; k0 < K; k0 += 64) {
        float4 av = make_float4(0.f, 0.f, 0.f, 0.f);
        if (row0 + ar < M) {
            ushort4 h4 = *(const ushort4*)(A + (size_t)(row0 + ar) * K + k0 + ak4);
            av = make_float4(bf2f(h4.x), bf2f(h4.y), bf2f(h4.z), bf2f(h4.w));
        }
        *(float4*)&As[ar][ak4] = av;
        *(float4*)&Bs[bk][bc4] = *(const float4*)(B + (size_t)(k0 + bk) * 16 + bc4);
        __syncthreads();
        #pragma unroll
        for (int kk = 0; kk < 64; ++kk)
            acc = fmaf(As[r][kk], Bs[kk][c], acc);
        __syncthreads();
    }
    if (row0 + r < M) C[(size_t)(row0 + r) * 16 + c] = acc;
}

// ---------------- fused MFMA edge MLPs -> dst-slot-ordered ebd / ebd2 ----------------
#define TSTR 72   // LDS tile row stride in bf16 elems (144 B: 16B-aligned frag reads, <=2-way banks)
__global__ __launch_bounds__(256) void edge_mlps_k(
    const float* __restrict__ kr, const int* __restrict__ rkd,
    const u16* __restrict__ w1f, const u16* __restrict__ w2f, const float* __restrict__ b2a,
    const u16* __restrict__ w3f, const u16* __restrict__ w4f, const float* __restrict__ b2b,
    u16* __restrict__ ebd, u16* __restrict__ ebd2)
{
    __shared__ __align__(16) u16 T[4][16 * TSTR];
    const int t = threadIdx.x, wv = t >> 6, lane = t & 63;
    const int lm = lane & 15, quad = lane >> 4;
    const int tile = blockIdx.x * 4 + wv;
    const int e0 = tile * 16;
    if (e0 >= E_TOT) return;
    u16* Tw = T[wv];

    // weight fragments -> VGPRs (per-lane)
    short8 W1[4], W2[2][4];
    #pragma unroll
    for (int nt = 0; nt < 4; ++nt) W1[nt] = *(const short8*)(w1f + ((size_t)nt * 64 + lane) * 8);
    #pragma unroll
    for (int ks = 0; ks < 2; ++ks)
        #pragma unroll
        for (int nt = 0; nt < 4; ++nt)
            W2[ks][nt] = *(const short8*)(w2f + (((size_t)ks * 4 + nt) * 64 + lane) * 8);
    short8 W3 = *(const short8*)(w3f + (size_t)lane * 8);
    short8 W4 = *(const short8*)(w4f + (size_t)lane * 8);
    float b2av[4];
    #pragma unroll
    for (int nt = 0; nt < 4; ++nt) b2av[nt] = b2a[nt * 16 + lm];
    float b2bv = b2b[lm];

    // A-frag from kr: edge m = e0+lm, k = quad*8+j (K=16 zero-padded to 32)
    short8 af = {};
    if (quad < 2) {
        const float* kp = kr + (size_t)(e0 + lm) * NC + quad * 8;
        float4 v0 = *(const float4*)kp;
        float4 v1 = *(const float4*)(kp + 4);
        u16 tmp[8] = {f2bf(v0.x), f2bf(v0.y), f2bf(v0.z), f2bf(v0.w),
                      f2bf(v1.x), f2bf(v1.y), f2bf(v1.z), f2bf(v1.w)};
        af = *(const short8*)tmp;
    }

    // ---- MLP1 layer 1: [16 edges x 64] = kr @ w1, leaky 0.2 ----
    f32x4 a1[4] = {};
    #pragma unroll
    for (int nt = 0; nt < 4; ++nt)
        a1[nt] = __builtin_amdgcn_mfma_f32_16x16x32_bf16(af, W1[nt], a1[nt], 0, 0, 0);
    #pragma unroll
    for (int nt = 0; nt < 4; ++nt)
        #pragma unroll
        for (int r = 0; r < 4; ++r) {
            float v = a1[nt][r];
            v = v > 0.f ? v : 0.2f * v;
            Tw[(quad * 4 + r) * TSTR + nt * 16 + lm] = f2bf(v);
        }
    __builtin_amdgcn_s_waitcnt(0);   // drain LDS writes before same-wave reads

    // ---- MLP1 layer 2: K=64 from LDS tile ----
    short8 a2[2];
    #pragma unroll
    for (int ks = 0; ks < 2; ++ks)
        a2[ks] = *(const short8*)&Tw[lm * TSTR + ks * 32 + quad * 8];
    f32x4 c2[4] = {};
    #pragma unroll
    for (int nt = 0; nt < 4; ++nt)
        #pragma unroll
        for (int ks = 0; ks < 2; ++ks)
            c2[nt] = __builtin_amdgcn_mfma_f32_16x16x32_bf16(a2[ks], W2[ks][nt], c2[nt], 0, 0, 0);
    // epilogue: + b2, exp -> LDS
    #pragma unroll
    for (int nt = 0; nt < 4; ++nt)
        #pragma unroll
        for (int r = 0; r < 4; ++r)
            Tw[(quad * 4 + r) * TSTR + nt * 16 + lm] = f2bf(__expf(c2[nt][r] + b2av[nt]));
    __builtin_amdgcn_s_waitcnt(0);
    // repack: 16B row-chunks scattered to dst-slot rows (8 lanes per 128B row)
    #pragma unroll
    for (int p = 0; p < 2; ++p) {
        int c = p * 64 + lane;
        int row = c >> 3, off = (c & 7) * 8;
        int rd = rkd[e0 + row];
        short8 v = *(const short8*)&Tw[row * TSTR + off];
        *(short8*)(ebd + (size_t)rd * HID + off) = v;
    }

    // ---- MLP2 (16->16->16), reuses kr A-frag ----
    f32x4 b1 = __builtin_amdgcn_mfma_f32_16x16x32_bf16(af, W3, (f32x4){}, 0, 0, 0);
    __builtin_amdgcn_s_waitcnt(0);   // eb repack reads done before overwrite
    #pragma unroll
    for (int r = 0; r < 4; ++r) {
        float v = b1[r];
        v = v > 0.f ? v : 0.2f * v;
        Tw[(quad * 4 + r) * TSTR + lm] = f2bf(v);
    }
    __builtin_amdgcn_s_waitcnt(0);
    // A-frag: cols 16..31 hold stale finite values, but W4 is zero there -> no effect
    short8 a3 = *(const short8*)&Tw[lm * TSTR + quad * 8];
    f32x4 c3 = __builtin_amdgcn_mfma_f32_16x16x32_bf16(a3, W4, (f32x4){}, 0, 0, 0);
    #pragma unroll
    for (int r = 0; r < 4; ++r)
        Tw[(quad * 4 + r) * TSTR + lm] = f2bf(__expf(c3[r] + b2bv));
    __builtin_amdgcn_s_waitcnt(0);
    if (lane < 32) {
        int row = lane >> 1, off = (lane & 1) * 8;
        int rd = rkd[e0 + row];
        short8 v = *(const short8*)&Tw[row * TSTR + off];
        *(short8*)(ebd2 + (size_t)rd * NCLS + off) = v;
    }
}

// ---------------- layer-1 softmax denom + pre-scaled fp8 gather table (wave per src) ----------------
__global__ __launch_bounds__(256) void s1inv_k(
    const u16* __restrict__ ebd, const int* __restrict__ src_off, const int* __restrict__ src_list,
    u16* __restrict__ xb)
{
    __shared__ float sinv[4][64];
    int gid = blockIdx.x * 256 + threadIdx.x;
    int wid = gid >> 6, lane = gid & 63, wv = threadIdx.x >> 6;
    if (wid >= N_NODES) return;
    int o0 = src_off[wid], o1 = src_off[wid + 1];
    float s0 = 0.f, s1 = 0.f, s2 = 0.f, s3 = 0.f;
    int i = o0;
    for (; i + 3 < o1; i += 4) {
        int l0 = src_list[i], l1 = src_list[i + 1], l2 = src_list[i + 2], l3 = src_list[i + 3];
        s0 += bf2f(ebd[(size_t)l0 * HID + lane]);
        s1 += bf2f(ebd[(size_t)l1 * HID + lane]);
        s2 += bf2f(ebd[(size_t)l2 * HID + lane]);
        s3 += bf2f(ebd[(size_t)l3 * HID + lane]);
    }
    for (; i < o1; ++i) {
        int sl = src_list[i];
        s0 += bf2f(ebd[(size_t)sl * HID + lane]);
    }
    sinv[wv][lane] = 1.f / (((s0 + s1) + (s2 + s3)) + 1e-16f);
    __builtin_amdgcn_s_waitcnt(0);   // LDS writes visible wave-wide

    const u16* xr = xb + (size_t)wid * H1 + lane * 8;    // 8 contiguous channels
    short8 x8 = *(const short8*)xr;
    float y[8];
    #pragma unroll
    for (int j = 0; j < 8; ++j)
        y[j] = bf2f((u16)x8[j]) * sinv[wv][(lane * 8 + j) & 63];
    int p0 = 0, p1 = 0;
    p0 = __builtin_amdgcn_cvt_pk_fp8_f32(y[0], y[1], p0, false);
    p0 = __builtin_amdgcn_cvt_pk_fp8_f32(y[2], y[3], p0, true);
    p1 = __builtin_amdgcn_cvt_pk_fp8_f32(y[4], y[5], p1, false);
    p1 = __builtin_amdgcn_cvt_pk_fp8_f32(y[6], y[7], p1, true);
    uint2 pk; pk.x = (unsigned)p0; pk.y = (unsigned)p1;
    *(uint2*)((u8*)xb + (size_t)wid * (H1 * 2) + lane * 8) = pk;   // fp8 row in first 512 B
}

// ---------------- message pass 1: wave per dst, sequential slots, fp8 gather, unroll 4 ----------------
__global__ __launch_bounds__(256) void msg1_k(
    const u16* __restrict__ ebd, const u8* __restrict__ xq,
    const int* __restrict__ dsrc, const int* __restrict__ dst_off,
    u16* __restrict__ aggb)
{
    int gid = blockIdx.x * 256 + threadIdx.x;
    int wid = gid >> 6, lane = gid & 63;
    if (wid >= N_NODES) return;
    int o0 = dst_off[wid], o1 = dst_off[wid + 1];
    const int a_off = (lane & 7) * 8;     // alpha channel block (ch = lane*8+j mod 64)
    float acc[8] = {};
    int i = o0;
    for (; i + 3 < o1; i += 4) {
        int s0 = __builtin_nontemporal_load(dsrc + i);
        int s1 = __builtin_nontemporal_load(dsrc + i + 1);
        int s2 = __builtin_nontemporal_load(dsrc + i + 2);
        int s3 = __builtin_nontemporal_load(dsrc + i + 3);
        short8 a0 = __builtin_nontemporal_load((const short8*)(ebd + (size_t)i * HID + a_off));
        short8 a1 = __builtin_nontemporal_load((const short8*)(ebd + (size_t)(i + 1) * HID + a_off));
        short8 a2 = __builtin_nontemporal_load((const short8*)(ebd + (size_t)(i + 2) * HID + a_off));
        short8 a3 = __builtin_nontemporal_load((const short8*)(ebd + (size_t)(i + 3) * HID + a_off));
        uint2 q0 = *(const uint2*)(xq + (size_t)s0 * 1024 + lane * 8);
        uint2 q1 = *(const uint2*)(xq + (size_t)s1 * 1024 + lane * 8);
        uint2 q2 = *(const uint2*)(xq + (size_t)s2 * 1024 + lane * 8);
        uint2 q3 = *(const uint2*)(xq + (size_t)s3 * 1024 + lane * 8);
        const uint2 qs[4] = {q0, q1, q2, q3};
        const short8 as[4] = {a0, a1, a2, a3};
        #pragma unroll
        for (int u = 0; u < 4; ++u) {
            f32x2 d0 = __builtin_amdgcn_cvt_pk_f32_fp8((int)qs[u].x, false);
            f32x2 d1 = __builtin_amdgcn_cvt_pk_f32_fp8((int)qs[u].x, true);
            f32x2 d2 = __builtin_amdgcn_cvt_pk_f32_fp8((int)qs[u].y, false);
            f32x2 d3 = __builtin_amdgcn_cvt_pk_f32_fp8((int)qs[u].y, true);
            float xv[8] = {d0.x, d0.y, d1.x, d1.y, d2.x, d2.y, d3.x, d3.y};
            #pragma unroll
            for (int j = 0; j < 8; ++j)
                acc[j] = fmaf(bf2f((u16)as[u][j]), xv[j], acc[j]);
        }
    }
    for (; i < o1; ++i) {
        int s = __builtin_nontemporal_load(dsrc + i);
        short8 a8 = __builtin_nontemporal_load((const short8*)(ebd + (size_t)i * HID + a_off));
        uint2 q = *(const uint2*)(xq + (size_t)s * 1024 + lane * 8);
        f32x2 d0 = __builtin_amdgcn_cvt_pk_f32_fp8((int)q.x, false);
        f32x2 d1 = __builtin_amdgcn_cvt_pk_f32_fp8((int)q.x, true);
        f32x2 d2 = __builtin_amdgcn_cvt_pk_f32_fp8((int)q.y, false);
        f32x2 d3 = __builtin_amdgcn_cvt_pk_f32_fp8((int)q.y, true);
        float xv[8] = {d0.x, d0.y, d1.x, d1.y, d2.x, d2.y, d3.x, d3.y};
        #pragma unroll
        for (int j = 0; j < 8; ++j)
            acc[j] = fmaf(bf2f((u16)a8[j]), xv[j], acc[j]);
    }
    u16 pk[8];
    #pragma unroll
    for (int j = 0; j < 8; ++j) pk[j] = f2bf(acc[j]);
    __builtin_nontemporal_store(*(const short8*)pk, (short8*)(aggb + (size_t)wid * H1 + lane * 8));
}

// ---------------- inverse denominator, layer 2 (16 threads per src) ----------------
__global__ __launch_bounds__(256) void s2sum_k(
    const u16* __restrict__ ebd2, const int* __restrict__ src_off, const int* __restrict__ src_list,
    float* __restrict__ inv2)
{
    int t = threadIdx.x;
    int g = blockIdx.x * 16 + (t >> 4), c = t & 15;
    if (g >= N_NODES) return;
    int o0 = src_off[g], o1 = src_off[g + 1];
    float sum = 0.f;
    for (int i = o0; i < o1; ++i) {
        int sl = src_list[i];
        sum += bf2f(ebd2[(size_t)sl * NCLS + c]);
    }
    inv2[(size_t)g * NCLS + c] = 1.f / (sum + 1e-16f);
}

// ---------------- message pass 2 (16 threads per dst), sequential slots ----------------
__global__ __launch_bounds__(256) void msg2_k(
    const u16* __restrict__ ebd2, const float* __restrict__ inv2,
    const float* __restrict__ xh2, const int* __restrict__ dsrc,
    const int* __restrict__ dst_off, float* __restrict__ agg2)
{
    int t = threadIdx.x;
    int g = blockIdx.x * 16 + (t >> 4), c = t & 15;
    if (g >= N_NODES) return;
    int o0 = dst_off[g], o1 = dst_off[g + 1];
    float acc = 0.f;
    for (int i = o0; i < o1; ++i) {
        int s = dsrc[i];
        float a = bf2f(ebd2[(size_t)i * NCLS + c]) * inv2[(size_t)s * NCLS + c];
        acc = fmaf(a, xh2[(size_t)s * NCLS + c], acc);
    }
    agg2[(size_t)g * NCLS + c] = acc;
}

// ---------------- final: o = agg2 + bias2 + alpha*p2; log_softmax ----------------
__global__ __launch_bounds__(256) void final_k(
    const float* __restrict__ agg2, const float* __restrict__ ep,
    const float* __restrict__ pw1, const float* __restrict__ pw2,
    const float* __restrict__ pb2, const float* __restrict__ bias,
    const float* __restrict__ alpha_p, float* __restrict__ out)
{
    __shared__ float s1w[256], s2w[256], sb[16], sbias[16];
    const int t = threadIdx.x;
    s1w[t] = pw1[t];
    s2w[t] = pw2[t];
    if (t < 16) { sb[t] = pb2[t]; sbias[t] = bias[t]; }
    __syncthreads();
    const int v = blockIdx.x * 256 + t;
    if (v >= N_NODES) return;
    float alpha = *alpha_p;
    float e_[16];
    #pragma unroll
    for (int j4 = 0; j4 < 16; j4 += 4) {
        float4 vv = *(const float4*)(ep + (size_t)v * 16 + j4);
        e_[j4] = vv.x; e_[j4 + 1] = vv.y; e_[j4 + 2] = vv.z; e_[j4 + 3] = vv.w;
    }
    float t2[16];
    #pragma unroll
    for (int c = 0; c < 16; ++c) {
        float s = 0.f;
        #pragma unroll
        for (int j = 0; j < 16; ++j) s = fmaf(e_[j], s1w[j * 16 + c], s);
        t2[c] = s > 0.f ? s : 0.2f * s;
    }
    float o[16];
    #pragma unroll
    for (int c4 = 0; c4 < 16; c4 += 4) {
        float4 ag = *(const float4*)(agg2 + (size_t)v * 16 + c4);
        float agv[4] = {ag.x, ag.y, ag.z, ag.w};
        #pragma unroll
        for (int q = 0; q < 4; ++q) {
            int c = c4 + q;
            float p = sb[c];
            #pragma unroll
            for (int j = 0; j < 16; ++j) p = fmaf(t2[j], s2w[j * 16 + c], p);
            p = p > 0.f ? p : 0.01f * p;
            o[c] = agv[q] + sbias[c] + alpha * p;
        }
    }
    float mx = o[0];
    #pragma unroll
    for (int c = 1; c < 16; ++c) mx = fmaxf(mx, o[c]);
    float se = 0.f;
    #pragma unroll
    for (int c = 0; c < 16; ++c) se += expf(o[c] - mx);
    float lse = mx + logf(se);
    #pragma unroll
    for (int c4 = 0; c4 < 16; c4 += 4)
        *(float4*)(out + (size_t)v * 16 + c4) =
            make_float4(o[c4] - lse, o[c4 + 1] - lse, o[c4 + 2] - lse, o[c4 + 3] - lse);
}

extern "C" void kernel_launch(void* const* d_in, const int* in_sizes, int n_in,
                              void* d_out, int out_size, void* d_ws, size_t ws_size,
                              hipStream_t stream) {
    const float* x    = (const float*)d_in[0];
    const int*   ei   = (const int*)d_in[1];
    const float* alpha= (const float*)d_in[2];
    const float* kr   = (const float*)d_in[3];
    const float* ep   = (const float*)d_in[4];
    const float* W1   = (const float*)d_in[5];
    const float* h1w1 = (const float*)d_in[6];
    const float* h1w2 = (const float*)d_in[7];
    const float* h1b2 = (const float*)d_in[8];
    const float* p1w1 = (const float*)d_in[9];
    const float* p1w2 = (const float*)d_in[10];
    const float* p1b2 = (const float*)d_in[11];
    const float* b1   = (const float*)d_in[12];
    const float* W2   = (const float*)d_in[13];
    const float* h2w1 = (const float*)d_in[14];
    const float* h2w2 = (const float*)d_in[15];
    const float* h2b2 = (const float*)d_in[16];
    const float* p2w1 = (const float*)d_in[17];
    const float* p2w2 = (const float*)d_in[18];
    const float* p2b2 = (const float*)d_in[19];
    const float* b2   = (const float*)d_in[20];
    float* out = (float*)d_out;

    // ---- workspace bump allocator (~242 MB) ----
    char* p = (char*)d_ws;
    auto alloc = [&](size_t bytes) { char* r = p; p += (bytes + 255) & ~(size_t)255; return r; };

    char* r0    = alloc((size_t)64 * M_PAD * 16);          // 51.25 MB: xb (bf16 Nx512 -> fp8 table), then t1p
    u16*  xb    = (u16*)r0;
    u16*  t1p   = (u16*)r0;
    u16*  aggb  = (u16*)alloc((size_t)N_NODES * H1 * 2);   // 51.2 MB bf16
    char* ebr   = alloc((size_t)E_TOT * HID * 2);          // 83.2 MB: ebd (dst-ordered), then hb (Nx512)
    u16*  ebd   = (u16*)ebr;
    u16*  hb    = (u16*)ebr;
    u16*  ebd2  = (u16*)alloc((size_t)E_TOT * NCLS * 2);   // 20.8 MB
    u16*  xp    = (u16*)alloc((size_t)16 * M_PAD * 16);    // 12.81 MB: xp (frag-major x)
    u16*  W1p   = (u16*)alloc((size_t)16 * H1 * 16);       // 128 KB
    u16*  p1w2p = (u16*)alloc((size_t)64 * H1 * 16);       // 512 KB
    u16*  w1f   = (u16*)alloc(2048 * 2);                   // mlp1 w1 frags
    u16*  w2f   = (u16*)alloc(4096 * 2);                   // mlp1 w2 frags
    u16*  w3f   = (u16*)alloc(512 * 2);                    // mlp2 w1 frags
    u16*  w4f   = (u16*)alloc(512 * 2);                    // mlp2 w2 frags
    int* src_cnt  = (int*)alloc(N_NODES * 4);
    int* dst_cnt  = (int*)alloc(N_NODES * 4);
    int* src_cur  = (int*)alloc(N_NODES * 4);
    int* dst_cur  = (int*)alloc(N_NODES * 4);
    int* partials = (int*)alloc(2 * NBLK * 4);
    int* src_off  = (int*)alloc((N_NODES + 1) * 4);
    int* dst_off  = (int*)alloc((N_NODES + 1) * 4);
    int* src_list = (int*)alloc((size_t)E_TOT * 4);        // dst-slot ids grouped by src
    int* rkd      = (int*)alloc((size_t)E_TOT * 4);        // e -> dst slot
    int* dsrc     = (int*)alloc((size_t)E_TOT * 4);        // dst slot -> src node
    float* xh2  = (float*)alloc((size_t)N_NODES * NCLS * 4);
    float* agg2 = (float*)alloc((size_t)N_NODES * NCLS * 4);
    float* inv2 = (float*)alloc((size_t)N_NODES * NCLS * 4);

    const dim3 blk(256);
    const int EB = (E_TOT + 255) / 256;
    const int WB = (N_NODES * 64 + 255) / 256;
    const int GB16 = (N_NODES + 15) / 16;
    const dim3 gmm(512 / 128, M_PAD / 128);                 // (4, 391)
    const int MLPB = (E_TOT / 16 + 3) / 4;

    // ---- CSR build + weight/layout conversion ----
    hipMemsetAsync(src_cnt, 0, (char*)partials - (char*)src_cnt, stream);
    count_k<<<EB, blk, 0, stream>>>(ei, src_cnt, dst_cnt);
    scanA_k<<<2 * NBLK, blk, 0, stream>>>(src_cnt, dst_cnt, partials);
    scanB_k<<<1, 512, 0, stream>>>(partials);
    scanC_k<<<2 * NBLK, blk, 0, stream>>>(src_cnt, dst_cnt, partials, src_off, dst_off);
    fill_csr_k<<<EB, blk, 0, stream>>>(ei, src_off, dst_off, src_cur, dst_cur, src_list, rkd, dsrc);
    conv_a_k<<<(16 * M_PAD + 255) / 256, blk, 0, stream>>>(x, xp, N_NODES, M_PAD, F_IN);
    conv_b_k<<<(16 * H1 + 255) / 256, blk, 0, stream>>>(W1, W1p, F_IN, H1);
    conv_b_k<<<(64 * H1 + 255) / 256, blk, 0, stream>>>(p1w2, p1w2p, H1, H1);
    wfrag_all_k<<<28, blk, 0, stream>>>(h1w1, h1w2, h2w1, h2w2, w1f, w2f, w3f, w4f);

    // ---- layer 1 ----
    mfma_gemm_k<0><<<gmm, blk, 0, stream>>>(xp, W1p, xb, N_NODES, M_PAD, H1, F_IN,
                                            nullptr, nullptr, nullptr, nullptr);
    edge_mlps_k<<<MLPB, blk, 0, stream>>>(kr, rkd, w1f, w2f, h1b2, w3f, w4f, h2b2, ebd, ebd2);
    s1inv_k<<<WB, blk, 0, stream>>>(ebd, src_off, src_list, xb);   // xb row -> fp8 y-table (first 512 B)
    msg1_k<<<WB, blk, 0, stream>>>(ebd, (const u8*)xb, dsrc, dst_off, aggb);
    gemm_t1_k<<<dim3(8, (N_NODES + 63) / 64), blk, 0, stream>>>(ep, p1w1, t1p);   // overwrites xb region
    mfma_gemm_k<3><<<gmm, blk, 0, stream>>>(t1p, p1w2p, hb, N_NODES, M_PAD, H1, H1,
                                            p1b2, aggb, b1, alpha);               // hb overwrites ebd region

    // ---- layer 2 ----
    gemm_n16_k<<<(N_NODES + 15) / 16, blk, 0, stream>>>(hb, W2, xh2, N_NODES, H1);
    s2sum_k<<<GB16, blk, 0, stream>>>(ebd2, src_off, src_list, inv2);
    msg2_k<<<GB16, blk, 0, stream>>>(ebd2, inv2, xh2, dsrc, dst_off, agg2);
    final_k<<<(N_NODES + 255) / 256, blk, 0, stream>>>(agg2, ep, p2w1, p2w2, p2b2, b2, alpha, out);
}